// Round 1
// 811.725 us; speedup vs baseline: 1.0318x; 1.0318x over previous
//
#include <hip/hip_runtime.h>
#include <hip/hip_bf16.h>
#include <math.h>

typedef __attribute__((ext_vector_type(8))) short short8;
typedef __attribute__((ext_vector_type(4))) float float4v;

// ---------------- helpers ----------------
__device__ __forceinline__ float wave_max64(float v) {
#pragma unroll
  for (int o = 32; o > 0; o >>= 1) v = fmaxf(v, __shfl_xor(v, o));
  return v;
}
__device__ __forceinline__ float wave_sum64(float v) {
#pragma unroll
  for (int o = 32; o > 0; o >>= 1) v += __shfl_xor(v, o);
  return v;
}
__device__ __forceinline__ float lrelu02(float v) { return v > 0.f ? v : 0.2f * v; }
__device__ __forceinline__ short bf16_rne(float f) {
  unsigned u = __builtin_bit_cast(unsigned, f);
  unsigned r = (u + 0x7FFFu + ((u >> 16) & 1u)) >> 16;
  return (short)r;
}

// ---------------- hist (both layers) + W1 prepack, merged ----------------
// blocks [0, nbE): histogram; blocks [nbE, nbE+19): prepack W1 into MFMA
// B-fragment order: Wp[((s*4+t)*64+lane)*8+j] = bf16(W[k][n]),
// k = s*32 + (lane>>4)*8 + j, n = t*16 + (lane&15); zero for k >= 602.
__global__ void hist_prepack_kernel(const int* __restrict__ dst1, const int* __restrict__ dst2,
                                    int* __restrict__ counts, const float* __restrict__ W,
                                    short* __restrict__ Wp, int E1, int E2, int N1D, int nbE) {
  int b = blockIdx.x;
  if (b < nbE) {
    int e = b * 256 + threadIdx.x;
    if (e < E1) atomicAdd(&counts[dst1[e]], 1);
    else if (e < E1 + E2) atomicAdd(&counts[N1D + dst2[e - E1]], 1);
  } else {
    int idx = (b - nbE) * 256 + threadIdx.x;  // over 19*4*64 = 4864
    if (idx >= 19 * 4 * 64) return;
    int lane = idx & 63;
    int t = (idx >> 6) & 3;
    int s = idx >> 8;
    int quad = lane >> 4, n = t * 16 + (lane & 15);
    short8 v;
#pragma unroll
    for (int j = 0; j < 8; j++) {
      int k = s * 32 + quad * 8 + j;
      v[j] = (k < 602) ? bf16_rne(W[k * 64 + n]) : (short)0;
    }
    *((short8*)Wp + idx) = v;
  }
}

// two-level scan over n = N1D + N2D elements
__global__ __launch_bounds__(256) void scan1_kernel(const int* __restrict__ counts,
                                                    int* __restrict__ offs,
                                                    int* __restrict__ bsum, int n) {
  __shared__ int ws[4], wpre[4];
  int tid = threadIdx.x, lane = tid & 63, w = tid >> 6;
  int i = blockIdx.x * 256 + tid;
  int v = (i < n) ? counts[i] : 0;
  int x = v;
#pragma unroll
  for (int o = 1; o < 64; o <<= 1) {
    int y = __shfl_up(x, o);
    if (lane >= o) x += y;
  }
  if (lane == 63) ws[w] = x;
  __syncthreads();
  if (tid == 0) {
    int run = 0;
#pragma unroll
    for (int k = 0; k < 4; k++) { wpre[k] = run; run += ws[k]; }
    bsum[blockIdx.x] = run;
  }
  __syncthreads();
  if (i < n) offs[i] = x - v + wpre[w];  // exclusive within block
}

__global__ __launch_bounds__(256) void scan2_kernel(int* __restrict__ bsum, int nb) {
  __shared__ int ws[4], wpre[4];
  int tid = threadIdx.x, lane = tid & 63, w = tid >> 6;
  int v = (tid < nb) ? bsum[tid] : 0;
  int x = v;
#pragma unroll
  for (int o = 1; o < 64; o <<= 1) {
    int y = __shfl_up(x, o);
    if (lane >= o) x += y;
  }
  if (lane == 63) ws[w] = x;
  __syncthreads();
  if (tid == 0) {
    int run = 0;
#pragma unroll
    for (int k = 0; k < 4; k++) { wpre[k] = run; run += ws[k]; }
  }
  __syncthreads();
  if (tid < nb) bsum[tid] = x - v + wpre[w];  // exclusive block prefixes
}

__global__ __launch_bounds__(256) void scan3_kernel(int* __restrict__ offs,
                                                    const int* __restrict__ bsum,
                                                    int n, int etot) {
  int i = blockIdx.x * 256 + threadIdx.x;
  if (i < n) offs[i] += bsum[blockIdx.x];
  if (i == 0) offs[n] = etot;  // sentinel
}

// ---------------- fused: GEMM1 (MFMA bf16) + attn-src epilogue + edge scatter --------
// blocks [0, nbG): hs1 = x[n_id1] @ W1 (wave computes 16 rows x 64 cols, no LDS),
//   with the per-head attn-src dot product reduced straight out of the accumulators:
//   col c = t*16+mrow = 8*(t*2+(mrow>>3)) + (mrow&7)  ->  head h = t*2+(mrow>>3),
//   so an 8-lane shfl_xor(1,2,4) reduce over mrow&7 yields ssrc1[r*8+h] for free
//   (saves the separate attn_src1 kernel's full 31 MB re-read of hs1).
// blocks [nbG, nbG+nbE): CSR payload scatter (independent of the GEMM; co-scheduled
//   here so its atomics hide under the HBM-bound GEMM instead of serializing).
__global__ __launch_bounds__(256) void gemm1_fused_kernel(
    const float* __restrict__ x, const int* __restrict__ n_id,
    const short* __restrict__ Wp, const float* __restrict__ as1,
    float* __restrict__ out, float* __restrict__ ssrc1, int M, int nbG,
    const int* __restrict__ dst1, const int* __restrict__ src1,
    const int* __restrict__ dst2, const int* __restrict__ src2,
    const int* __restrict__ offs, int* __restrict__ cursor,
    int* __restrict__ epay, int E1, int E2, int N1D) {
  if (blockIdx.x >= nbG) {
    // scatter stores the SOURCE NODE id (payload) directly into the CSR slot:
    // aggregation is order-independent, so slot order doesn't matter.
    int e = (blockIdx.x - nbG) * 256 + threadIdx.x;
    if (e < E1) {
      int d = dst1[e];
      int pos = offs[d] + atomicAdd(&cursor[d], 1);
      epay[pos] = src1[e];
    } else if (e < E1 + E2) {
      int e2 = e - E1;
      int d = N1D + dst2[e2];
      int pos = offs[d] + atomicAdd(&cursor[d], 1);
      epay[pos] = src2[e2];
    }
    return;
  }
  constexpr int K = 602, NSTEP = 19;
  int tid = threadIdx.x;
  int wid = tid >> 6, lane = tid & 63;
  int quad = lane >> 4, mrow = lane & 15;
  int r = blockIdx.x * 64 + wid * 16 + mrow;
  int grow = n_id[r < M ? r : M - 1];
  const float* xrow = x + (size_t)grow * K;
  float4v acc[4] = {{0.f, 0.f, 0.f, 0.f}, {0.f, 0.f, 0.f, 0.f},
                    {0.f, 0.f, 0.f, 0.f}, {0.f, 0.f, 0.f, 0.f}};
  for (int s = 0; s < NSTEP; s++) {
    int k0 = s * 32 + quad * 8;
    float af[8];
    if (k0 + 8 <= K) {  // 8B-aligned (row pitch 602 even, k0 even)
#pragma unroll
      for (int j = 0; j < 8; j += 2) {
        float2 v = *(const float2*)(xrow + k0 + j);
        af[j] = v.x;
        af[j + 1] = v.y;
      }
    } else {
#pragma unroll
      for (int j = 0; j < 8; j++) af[j] = (k0 + j < K) ? xrow[k0 + j] : 0.f;
    }
    short8 a;
#pragma unroll
    for (int j = 0; j < 8; j++) a[j] = bf16_rne(af[j]);
    const short8* wp = (const short8*)Wp + (size_t)s * 256 + lane;
#pragma unroll
    for (int t = 0; t < 4; t++) {
      short8 b = wp[t * 64];
      acc[t] = __builtin_amdgcn_mfma_f32_16x16x32_bf16(a, b, acc[t], 0, 0, 0);
    }
  }
  int rb = blockIdx.x * 64 + wid * 16;
#pragma unroll
  for (int t = 0; t < 4; t++) {
#pragma unroll
    for (int j = 0; j < 4; j++) {
      int rr = rb + quad * 4 + j;  // C/D: col = lane&15, row = quad*4 + reg
      if (rr < M) out[(size_t)rr * 64 + t * 16 + mrow] = acc[t][j];
    }
  }
  // attn-src epilogue: ssrc1[r*8+h] = sum_{c in head h} hs1[r][c] * as1_flat[c]
  float afv[4];
#pragma unroll
  for (int t = 0; t < 4; t++) afv[t] = as1[t * 16 + mrow];  // as1_flat[c], c=t*16+mrow
#pragma unroll
  for (int t = 0; t < 4; t++) {
#pragma unroll
    for (int j = 0; j < 4; j++) {
      float v = acc[t][j] * afv[t];
      v += __shfl_xor(v, 1);  // reduce over mrow&7 (lane bits 0..2)
      v += __shfl_xor(v, 2);
      v += __shfl_xor(v, 4);
      if ((lane & 7) == 0) {
        int rr = rb + quad * 4 + j;
        if (rr < M) ssrc1[rr * 8 + t * 2 + ((lane >> 3) & 1)] = v;
      }
    }
  }
}

// ---------------- aggregation layer 1 (online softmax, fused attn_dst)
//                  + fused GEMM2 / attn-src2 tail -----------------------------
// At the end of each wave, the full 64-element h1 row (post bias+ELU) lives in
// registers, one element per lane, and h1 has no other consumer -> compute
// hs2[wid] = h1_row @ W2 and ssrc2[wid] right here via a per-wave LDS row
// broadcast (eliminates the h1 buffer round-trip and the gemm2 launch).
__global__ __launch_bounds__(256) void agg1_kernel(
    const int* __restrict__ offs, const int* __restrict__ srcs,
    const float* __restrict__ s_src, const int* __restrict__ res,
    const float* __restrict__ ad, const float* __restrict__ hs1,
    const float* __restrict__ bias, const float* __restrict__ W2,
    const float* __restrict__ as2, float* __restrict__ hs2,
    float* __restrict__ ssrc2, int n_dst) {
  constexpr int C = 41;
  __shared__ float Ws[64 * C];
  __shared__ float rowsh[4][64];
  for (int i = threadIdx.x; i < 64 * C; i += 256) Ws[i] = W2[i];
  __syncthreads();
  int wid = (blockIdx.x * blockDim.x + threadIdx.x) >> 6;
  if (wid >= n_dst) return;
  int lane = threadIdx.x & 63;
  int w = threadIdx.x >> 6;
  int h = lane >> 3;
  // fused attn_dst1: sd[h] = dot(hs1[res[wid], h*8:h*8+8], ad[h*8:h*8+8])
  int node = res[wid];
  float v = hs1[(size_t)node * 64 + lane] * ad[lane];
  v += __shfl_xor(v, 1);
  v += __shfl_xor(v, 2);
  v += __shfl_xor(v, 4);
  float sd = v;  // per-8-lane head group sum
  int beg = offs[wid], end = offs[wid + 1];
  float mx = -1e30f, den = 0.f, acc = 0.f;
  for (int i = beg; i < end; i += 8) {
    int m = end - i; if (m > 8) m = 8;
    int sr[8]; float ss[8], row[8];
#pragma unroll
    for (int j = 0; j < 8; j++) sr[j] = srcs[i + (j < m ? j : 0)];
#pragma unroll
    for (int j = 0; j < 8; j++) ss[j] = s_src[sr[j] * 8 + h];
#pragma unroll
    for (int j = 0; j < 8; j++) row[j] = hs1[(size_t)sr[j] * 64 + lane];
    float p[8];
#pragma unroll
    for (int j = 0; j < 8; j++) p[j] = (j < m) ? lrelu02(ss[j] + sd) : -1e30f;
    float bm = mx;
#pragma unroll
    for (int j = 0; j < 8; j++) bm = fmaxf(bm, p[j]);
    float scale = __expf(mx - bm);
    den *= scale;
    acc *= scale;
#pragma unroll
    for (int j = 0; j < 8; j++) {
      float w2 = __expf(p[j] - bm);
      den += w2;
      acc += w2 * row[j];
    }
    mx = bm;
  }
  float val = (end > beg) ? acc / den : 0.f;
  val += bias[lane];
  val = val > 0.f ? val : __expf(val) - 1.f;  // ELU  -> h1[wid][lane]
  // fused GEMM2 row: hs2[wid][c] = sum_k h1[wid][k] * W2[k][c]
  // (wave-local LDS transpose: write own row, read broadcast — no barrier needed,
  //  producer and consumer are the same wave; compiler orders via lgkmcnt)
  rowsh[w][lane] = val;
  float acc2 = 0.f;
  if (lane < C) {
#pragma unroll 8
    for (int k = 0; k < 64; k++) acc2 += rowsh[w][k] * Ws[k * C + lane];
  }
  float tt = (lane < C) ? acc2 * as2[lane] : 0.f;
  tt = wave_sum64(tt);
  if (lane == 0) ssrc2[wid] = tt;
  if (lane < C) hs2[(size_t)wid * C + lane] = acc2;
}

// ---------------- aggregation layer 2 (online softmax, fused attn_dst) + log_softmax ----
__global__ __launch_bounds__(256) void agg2_kernel(
    const int* __restrict__ offs, const int* __restrict__ srcs,
    const float* __restrict__ s_src, const int* __restrict__ res,
    const float* __restrict__ ad, const float* __restrict__ hs2,
    const float* __restrict__ bias, float* __restrict__ out, int n_dst) {
  constexpr int C = 41;
  int wid = (blockIdx.x * blockDim.x + threadIdx.x) >> 6;
  if (wid >= n_dst) return;
  int lane = threadIdx.x & 63;
  bool act = lane < C;
  // fused attn_dst2: sd = dot(hs2[res[wid]], ad)
  int node = res[wid];
  float dv = act ? hs2[(size_t)node * C + lane] * ad[lane] : 0.f;
  float sd = wave_sum64(dv);
  int beg = offs[wid], end = offs[wid + 1];
  float mx = -1e30f, den = 0.f, acc = 0.f;
  for (int i = beg; i < end; i += 8) {
    int m = end - i; if (m > 8) m = 8;
    int sr[8]; float ss[8], row[8];
#pragma unroll
    for (int j = 0; j < 8; j++) sr[j] = srcs[i + (j < m ? j : 0)];
#pragma unroll
    for (int j = 0; j < 8; j++) ss[j] = s_src[sr[j]];
#pragma unroll
    for (int j = 0; j < 8; j++) row[j] = act ? hs2[(size_t)sr[j] * C + lane] : 0.f;
    float p[8];
#pragma unroll
    for (int j = 0; j < 8; j++) p[j] = (j < m) ? lrelu02(ss[j] + sd) : -1e30f;
    float bm = mx;
#pragma unroll
    for (int j = 0; j < 8; j++) bm = fmaxf(bm, p[j]);
    float scale = __expf(mx - bm);
    den *= scale;
    acc *= scale;
#pragma unroll
    for (int j = 0; j < 8; j++) {
      float w = __expf(p[j] - bm);
      den += w;
      acc += w * row[j];
    }
    mx = bm;
  }
  float val = (end > beg) ? acc / den : 0.f;
  if (act) val += bias[lane];
  float lv = act ? val : -1e30f;
  float m2 = wave_max64(lv);
  float ex = act ? __expf(val - m2) : 0.f;
  float ssum = wave_sum64(ex);
  if (act) out[(size_t)wid * C + lane] = val - m2 - __logf(ssum);
}

// ---------------- launch ----------------
extern "C" void kernel_launch(void* const* d_in, const int* in_sizes, int n_in,
                              void* d_out, int out_size, void* d_ws, size_t ws_size,
                              hipStream_t stream) {
  const float* x    = (const float*)d_in[0];
  const int* n_id1  = (const int*)d_in[1];
  const int* res1   = (const int*)d_in[2];
  const int* esrc1  = (const int*)d_in[3];
  const int* edst1  = (const int*)d_in[4];
  const int* res2   = (const int*)d_in[5];
  const int* esrc2  = (const int*)d_in[6];
  const int* edst2  = (const int*)d_in[7];
  const float* W1   = (const float*)d_in[8];
  const float* as1  = (const float*)d_in[9];
  const float* ad1  = (const float*)d_in[10];
  const float* b1   = (const float*)d_in[11];
  const float* W2   = (const float*)d_in[12];
  const float* as2  = (const float*)d_in[13];
  const float* ad2  = (const float*)d_in[14];
  const float* b2   = (const float*)d_in[15];
  float* out = (float*)d_out;

  const int N1  = in_sizes[1];  // 120000
  const int N1D = in_sizes[2];  // 30000
  const int E1  = in_sizes[3];  // 960000
  const int N2D = in_sizes[5];  // 6000
  const int E2  = in_sizes[6];  // 192000
  const int NTOT = N1D + N2D;
  const int ETOT = E1 + E2;

  char* w = (char*)d_ws;
  size_t off = 0;
  auto alloc = [&](size_t bytes) -> void* {
    void* p = (void*)(w + off);
    off += (bytes + 255) & ~(size_t)255;
    return p;
  };
  float* hs1   = (float*)alloc((size_t)N1 * 64 * 4);
  float* ssrc1 = (float*)alloc((size_t)N1 * 8 * 4);
  float* hs2   = (float*)alloc((size_t)N1D * 41 * 4);
  float* ssrc2 = (float*)alloc((size_t)N1D * 4);
  // counts+cursor in ONE contiguous alloc: the single memset below must cover
  // both exactly (round-2 bug: separate 256-aligned allocs left a 128 B
  // poisoned gap inside cursor -> wild writes -> GPU abort).
  int* counts  = (int*)alloc((size_t)2 * NTOT * 4);
  int* cursor  = counts + NTOT;
  int* offs    = (int*)alloc((size_t)(NTOT + 1) * 4);
  int* bsum    = (int*)alloc((size_t)256 * 4);
  int* epay    = (int*)alloc((size_t)ETOT * 4);
  short* Wp    = (short*)alloc((size_t)19 * 4 * 64 * 8 * 2);
  (void)ws_size; (void)n_in; (void)out_size;

  hipMemsetAsync(counts, 0, (size_t)2 * NTOT * 4, stream);  // counts + cursor exactly

  // CSR build (hist fused with W1 prepack), scan
  const int nbE = (ETOT + 255) / 256;
  const int nb = (NTOT + 255) / 256;  // 141
  hist_prepack_kernel<<<nbE + 19, 256, 0, stream>>>(edst1, edst2, counts, W1, Wp, E1, E2, N1D, nbE);
  scan1_kernel<<<nb, 256, 0, stream>>>(counts, offs, bsum, NTOT);
  scan2_kernel<<<1, 256, 0, stream>>>(bsum, nb);
  scan3_kernel<<<nb, 256, 0, stream>>>(offs, bsum, NTOT, ETOT);

  // layer 1: GEMM1 + attn-src epilogue, with the CSR payload scatter co-scheduled
  // as trailing blocks of the same launch (independent work, hides under the
  // HBM-bound GEMM instead of serializing on the stream)
  const int nbG = (N1 + 63) / 64;
  gemm1_fused_kernel<<<nbG + nbE, 256, 0, stream>>>(
      x, n_id1, Wp, as1, hs1, ssrc1, N1, nbG,
      edst1, esrc1, edst2, esrc2, offs, cursor, epay, E1, E2, N1D);
  agg1_kernel<<<(N1D + 3) / 4, 256, 0, stream>>>(offs, epay, ssrc1, res1, ad1, hs1, b1,
                                                 W2, as2, hs2, ssrc2, N1D);

  // layer 2 (CSR segment 2 lives at offs + N1D, payload is layer-2 src node id)
  agg2_kernel<<<(N2D + 3) / 4, 256, 0, stream>>>(offs + N1D, epay, ssrc2, res2, ad2, hs2, b2, out, N2D);
}

// Round 2
// 785.432 us; speedup vs baseline: 1.0663x; 1.0335x over previous
//
#include <hip/hip_runtime.h>
#include <hip/hip_bf16.h>
#include <math.h>

typedef __attribute__((ext_vector_type(8))) short short8;
typedef __attribute__((ext_vector_type(4))) float float4v;
typedef unsigned short ushort_t;

// ---------------- helpers ----------------
__device__ __forceinline__ float wave_max64(float v) {
#pragma unroll
  for (int o = 32; o > 0; o >>= 1) v = fmaxf(v, __shfl_xor(v, o));
  return v;
}
__device__ __forceinline__ float wave_sum64(float v) {
#pragma unroll
  for (int o = 32; o > 0; o >>= 1) v += __shfl_xor(v, o);
  return v;
}
__device__ __forceinline__ int wave_isum64(int v) {
#pragma unroll
  for (int o = 32; o > 0; o >>= 1) v += __shfl_xor(v, o);
  return v;
}
__device__ __forceinline__ float lrelu02(float v) { return v > 0.f ? v : 0.2f * v; }
__device__ __forceinline__ short bf16_rne(float f) {
  unsigned u = __builtin_bit_cast(unsigned, f);
  unsigned r = (u + 0x7FFFu + ((u >> 16) & 1u)) >> 16;
  return (short)r;
}
__device__ __forceinline__ float bf16_to_f32(ushort_t u) {
  return __builtin_bit_cast(float, ((unsigned)u) << 16);
}

// ---------------- hist (both layers, records per-edge rank) + W1 prepack ----------------
// blocks [0, nbE): histogram; the atomicAdd return value IS the edge's unique rank
// within its dst segment -> stored to erank so the scatter pass needs no second
// atomic (cursor array eliminated entirely).
// blocks [nbE, nbE+19): prepack W1 into MFMA B-fragment order:
// Wp[((s*4+t)*64+lane)*8+j] = bf16(W[k][n]), k = s*32+(lane>>4)*8+j, n = t*16+(lane&15).
__global__ void hist_prepack_kernel(const int* __restrict__ dst1, const int* __restrict__ dst2,
                                    int* __restrict__ counts, int* __restrict__ erank,
                                    const float* __restrict__ W,
                                    short* __restrict__ Wp, int E1, int E2, int N1D, int nbE) {
  int b = blockIdx.x;
  if (b < nbE) {
    int e = b * 256 + threadIdx.x;
    if (e < E1) {
      erank[e] = atomicAdd(&counts[dst1[e]], 1);
    } else if (e < E1 + E2) {
      erank[e] = atomicAdd(&counts[N1D + dst2[e - E1]], 1);
    }
  } else {
    int idx = (b - nbE) * 256 + threadIdx.x;  // over 19*4*64 = 4864
    if (idx >= 19 * 4 * 64) return;
    int lane = idx & 63;
    int t = (idx >> 6) & 3;
    int s = idx >> 8;
    int quad = lane >> 4, n = t * 16 + (lane & 15);
    short8 v;
#pragma unroll
    for (int j = 0; j < 8; j++) {
      int k = s * 32 + quad * 8 + j;
      v[j] = (k < 602) ? bf16_rne(W[k * 64 + n]) : (short)0;
    }
    *((short8*)Wp + idx) = v;
  }
}

// scan pass 1: per-block exclusive scan, block totals to bsum
__global__ __launch_bounds__(256) void scan1_kernel(const int* __restrict__ counts,
                                                    int* __restrict__ offs,
                                                    int* __restrict__ bsum, int n) {
  __shared__ int ws[4], wpre[4];
  int tid = threadIdx.x, lane = tid & 63, w = tid >> 6;
  int i = blockIdx.x * 256 + tid;
  int v = (i < n) ? counts[i] : 0;
  int x = v;
#pragma unroll
  for (int o = 1; o < 64; o <<= 1) {
    int y = __shfl_up(x, o);
    if (lane >= o) x += y;
  }
  if (lane == 63) ws[w] = x;
  __syncthreads();
  if (tid == 0) {
    int run = 0;
#pragma unroll
    for (int k = 0; k < 4; k++) { wpre[k] = run; run += ws[k]; }
    bsum[blockIdx.x] = run;
  }
  __syncthreads();
  if (i < n) offs[i] = x - v + wpre[w];  // exclusive within block
}

// scan pass 2 (fused old scan2+scan3): each block reduces bsum[0..bid) itself
// (nb = 141 <= 256 threads, so one masked wave-reduce covers it) and adds the
// prefix to its 256 offsets. Saves a whole dispatch.
__global__ __launch_bounds__(256) void scan3_kernel(int* __restrict__ offs,
                                                    const int* __restrict__ bsum,
                                                    int n, int etot, int nb) {
  __shared__ int wsum[4];
  int tid = threadIdx.x, lane = tid & 63, w = tid >> 6;
  int bid = blockIdx.x;
  int v = (tid < nb && tid < bid) ? bsum[tid] : 0;
  v = wave_isum64(v);
  if (lane == 0) wsum[w] = v;
  __syncthreads();
  int pre = wsum[0] + wsum[1] + wsum[2] + wsum[3];
  int i = bid * 256 + tid;
  if (i < n) offs[i] += pre;
  if (i == 0) offs[n] = etot;  // sentinel
}

// ---------------- fused: edge scatter + GEMM1 (MFMA bf16) + attn-src epilogue --------
// blocks [0, nbE): CSR payload scatter — placed FIRST so its gather/store latency
//   hides under the HBM-bound GEMM blocks that follow (a trailing scatter phase
//   would run as a low-BW atomic tail after the GEMM drains). Pure load/store now:
//   pos = offs[d] + erank[e] (rank captured in the histogram's atomicAdd).
//   Payload is the SOURCE NODE id: aggregation is order-independent.
// blocks [nbE, nbE+nbG): hs1 = bf16(x[n_id1] @ W1) (wave computes 16 rows x 64 cols),
//   with the per-head attn-src dot product reduced straight out of the f32
//   accumulators (full precision for the logits; only the STORED hs1 is bf16 —
//   halves agg1's 246 MB row-gather and this kernel's 31 MB write):
//   col c = t*16+mrow = 8*(t*2+(mrow>>3)) + (mrow&7)  ->  head h = t*2+(mrow>>3),
//   8-lane shfl_xor(1,2,4) reduce over mrow&7 yields ssrc1[r*8+h] for free.
__global__ __launch_bounds__(256) void gemm1_fused_kernel(
    const float* __restrict__ x, const int* __restrict__ n_id,
    const short* __restrict__ Wp, const float* __restrict__ as1,
    ushort_t* __restrict__ out, float* __restrict__ ssrc1, int M, int nbE,
    const int* __restrict__ dst1, const int* __restrict__ src1,
    const int* __restrict__ dst2, const int* __restrict__ src2,
    const int* __restrict__ offs, const int* __restrict__ erank,
    int* __restrict__ epay, int E1, int E2, int N1D) {
  if (blockIdx.x < nbE) {
    int e = blockIdx.x * 256 + threadIdx.x;
    if (e < E1) {
      int d = dst1[e];
      epay[offs[d] + erank[e]] = src1[e];
    } else if (e < E1 + E2) {
      int e2 = e - E1;
      int d = N1D + dst2[e2];
      epay[offs[d] + erank[e]] = src2[e2];
    }
    return;
  }
  constexpr int K = 602, NSTEP = 19;
  int gb = blockIdx.x - nbE;
  int tid = threadIdx.x;
  int wid = tid >> 6, lane = tid & 63;
  int quad = lane >> 4, mrow = lane & 15;
  int r = gb * 64 + wid * 16 + mrow;
  int grow = n_id[r < M ? r : M - 1];
  const float* xrow = x + (size_t)grow * K;
  float4v acc[4] = {{0.f, 0.f, 0.f, 0.f}, {0.f, 0.f, 0.f, 0.f},
                    {0.f, 0.f, 0.f, 0.f}, {0.f, 0.f, 0.f, 0.f}};
  for (int s = 0; s < NSTEP; s++) {
    int k0 = s * 32 + quad * 8;
    float af[8];
    if (k0 + 8 <= K) {  // 8B-aligned (row pitch 602 even, k0 even)
#pragma unroll
      for (int j = 0; j < 8; j += 2) {
        float2 v = *(const float2*)(xrow + k0 + j);
        af[j] = v.x;
        af[j + 1] = v.y;
      }
    } else {
#pragma unroll
      for (int j = 0; j < 8; j++) af[j] = (k0 + j < K) ? xrow[k0 + j] : 0.f;
    }
    short8 a;
#pragma unroll
    for (int j = 0; j < 8; j++) a[j] = bf16_rne(af[j]);
    const short8* wp = (const short8*)Wp + (size_t)s * 256 + lane;
#pragma unroll
    for (int t = 0; t < 4; t++) {
      short8 b = wp[t * 64];
      acc[t] = __builtin_amdgcn_mfma_f32_16x16x32_bf16(a, b, acc[t], 0, 0, 0);
    }
  }
  int rb = gb * 64 + wid * 16;
#pragma unroll
  for (int t = 0; t < 4; t++) {
#pragma unroll
    for (int j = 0; j < 4; j++) {
      int rr = rb + quad * 4 + j;  // C/D: col = lane&15, row = quad*4 + reg
      if (rr < M) out[(size_t)rr * 64 + t * 16 + mrow] = (ushort_t)bf16_rne(acc[t][j]);
    }
  }
  // attn-src epilogue (f32 accumulators -> full-precision logits)
  float afv[4];
#pragma unroll
  for (int t = 0; t < 4; t++) afv[t] = as1[t * 16 + mrow];  // as1_flat[c], c=t*16+mrow
#pragma unroll
  for (int t = 0; t < 4; t++) {
#pragma unroll
    for (int j = 0; j < 4; j++) {
      float v = acc[t][j] * afv[t];
      v += __shfl_xor(v, 1);  // reduce over mrow&7 (lane bits 0..2)
      v += __shfl_xor(v, 2);
      v += __shfl_xor(v, 4);
      if ((lane & 7) == 0) {
        int rr = rb + quad * 4 + j;
        if (rr < M) ssrc1[rr * 8 + t * 2 + ((lane >> 3) & 1)] = v;
      }
    }
  }
}

// ---------------- aggregation layer 1 (online softmax, fused attn_dst)
//                  + fused GEMM2 / attn-src2 tail -----------------------------
// hs1 is stored bf16 (pure intermediate; f32 accumulation here, so only per-value
// rounding noise ~2^-9 enters the convex combination). At the end of each wave
// the full 64-element h1 row (post bias+ELU) lives in registers -> compute
// hs2[wid] = h1_row @ W2 and ssrc2[wid] right here via a per-wave LDS row
// broadcast (no h1 buffer round-trip, no gemm2 launch).
__global__ __launch_bounds__(256) void agg1_kernel(
    const int* __restrict__ offs, const int* __restrict__ srcs,
    const float* __restrict__ s_src, const int* __restrict__ res,
    const float* __restrict__ ad, const ushort_t* __restrict__ hs1,
    const float* __restrict__ bias, const float* __restrict__ W2,
    const float* __restrict__ as2, float* __restrict__ hs2,
    float* __restrict__ ssrc2, int n_dst) {
  constexpr int C = 41;
  __shared__ float Ws[64 * C];
  __shared__ float rowsh[4][64];
  for (int i = threadIdx.x; i < 64 * C; i += 256) Ws[i] = W2[i];
  __syncthreads();
  int wid = (blockIdx.x * blockDim.x + threadIdx.x) >> 6;
  if (wid >= n_dst) return;
  int lane = threadIdx.x & 63;
  int w = threadIdx.x >> 6;
  int h = lane >> 3;
  // fused attn_dst1: sd[h] = dot(hs1[res[wid], h*8:h*8+8], ad[h*8:h*8+8])
  int node = res[wid];
  float v = bf16_to_f32(hs1[(size_t)node * 64 + lane]) * ad[lane];
  v += __shfl_xor(v, 1);
  v += __shfl_xor(v, 2);
  v += __shfl_xor(v, 4);
  float sd = v;  // per-8-lane head group sum
  int beg = offs[wid], end = offs[wid + 1];
  float mx = -1e30f, den = 0.f, acc = 0.f;
  for (int i = beg; i < end; i += 8) {
    int m = end - i; if (m > 8) m = 8;
    int sr[8]; float ss[8], row[8];
#pragma unroll
    for (int j = 0; j < 8; j++) sr[j] = srcs[i + (j < m ? j : 0)];
#pragma unroll
    for (int j = 0; j < 8; j++) ss[j] = s_src[sr[j] * 8 + h];
#pragma unroll
    for (int j = 0; j < 8; j++) row[j] = bf16_to_f32(hs1[(size_t)sr[j] * 64 + lane]);
    float p[8];
#pragma unroll
    for (int j = 0; j < 8; j++) p[j] = (j < m) ? lrelu02(ss[j] + sd) : -1e30f;
    float bm = mx;
#pragma unroll
    for (int j = 0; j < 8; j++) bm = fmaxf(bm, p[j]);
    float scale = __expf(mx - bm);
    den *= scale;
    acc *= scale;
#pragma unroll
    for (int j = 0; j < 8; j++) {
      float w2 = __expf(p[j] - bm);
      den += w2;
      acc += w2 * row[j];
    }
    mx = bm;
  }
  float val = (end > beg) ? acc / den : 0.f;
  val += bias[lane];
  val = val > 0.f ? val : __expf(val) - 1.f;  // ELU  -> h1[wid][lane]
  // fused GEMM2 row: hs2[wid][c] = sum_k h1[wid][k] * W2[k][c]
  // (wave-local LDS transpose: write own row, read broadcast — producer and
  //  consumer are the same wave; compiler orders via lgkmcnt)
  rowsh[w][lane] = val;
  float acc2 = 0.f;
  if (lane < C) {
#pragma unroll 8
    for (int k = 0; k < 64; k++) acc2 += rowsh[w][k] * Ws[k * C + lane];
  }
  float tt = (lane < C) ? acc2 * as2[lane] : 0.f;
  tt = wave_sum64(tt);
  if (lane == 0) ssrc2[wid] = tt;
  if (lane < C) hs2[(size_t)wid * C + lane] = acc2;
}

// ---------------- aggregation layer 2 (online softmax, fused attn_dst) + log_softmax ----
__global__ __launch_bounds__(256) void agg2_kernel(
    const int* __restrict__ offs, const int* __restrict__ srcs,
    const float* __restrict__ s_src, const int* __restrict__ res,
    const float* __restrict__ ad, const float* __restrict__ hs2,
    const float* __restrict__ bias, float* __restrict__ out, int n_dst) {
  constexpr int C = 41;
  int wid = (blockIdx.x * blockDim.x + threadIdx.x) >> 6;
  if (wid >= n_dst) return;
  int lane = threadIdx.x & 63;
  bool act = lane < C;
  // fused attn_dst2: sd = dot(hs2[res[wid]], ad)
  int node = res[wid];
  float dv = act ? hs2[(size_t)node * C + lane] * ad[lane] : 0.f;
  float sd = wave_sum64(dv);
  int beg = offs[wid], end = offs[wid + 1];
  float mx = -1e30f, den = 0.f, acc = 0.f;
  for (int i = beg; i < end; i += 8) {
    int m = end - i; if (m > 8) m = 8;
    int sr[8]; float ss[8], row[8];
#pragma unroll
    for (int j = 0; j < 8; j++) sr[j] = srcs[i + (j < m ? j : 0)];
#pragma unroll
    for (int j = 0; j < 8; j++) ss[j] = s_src[sr[j]];
#pragma unroll
    for (int j = 0; j < 8; j++) row[j] = act ? hs2[(size_t)sr[j] * C + lane] : 0.f;
    float p[8];
#pragma unroll
    for (int j = 0; j < 8; j++) p[j] = (j < m) ? lrelu02(ss[j] + sd) : -1e30f;
    float bm = mx;
#pragma unroll
    for (int j = 0; j < 8; j++) bm = fmaxf(bm, p[j]);
    float scale = __expf(mx - bm);
    den *= scale;
    acc *= scale;
#pragma unroll
    for (int j = 0; j < 8; j++) {
      float w = __expf(p[j] - bm);
      den += w;
      acc += w * row[j];
    }
    mx = bm;
  }
  float val = (end > beg) ? acc / den : 0.f;
  if (act) val += bias[lane];
  float lv = act ? val : -1e30f;
  float m2 = wave_max64(lv);
  float ex = act ? __expf(val - m2) : 0.f;
  float ssum = wave_sum64(ex);
  if (act) out[(size_t)wid * C + lane] = val - m2 - __logf(ssum);
}

// ---------------- launch ----------------
extern "C" void kernel_launch(void* const* d_in, const int* in_sizes, int n_in,
                              void* d_out, int out_size, void* d_ws, size_t ws_size,
                              hipStream_t stream) {
  const float* x    = (const float*)d_in[0];
  const int* n_id1  = (const int*)d_in[1];
  const int* res1   = (const int*)d_in[2];
  const int* esrc1  = (const int*)d_in[3];
  const int* edst1  = (const int*)d_in[4];
  const int* res2   = (const int*)d_in[5];
  const int* esrc2  = (const int*)d_in[6];
  const int* edst2  = (const int*)d_in[7];
  const float* W1   = (const float*)d_in[8];
  const float* as1  = (const float*)d_in[9];
  const float* ad1  = (const float*)d_in[10];
  const float* b1   = (const float*)d_in[11];
  const float* W2   = (const float*)d_in[12];
  const float* as2  = (const float*)d_in[13];
  const float* ad2  = (const float*)d_in[14];
  const float* b2   = (const float*)d_in[15];
  float* out = (float*)d_out;

  const int N1  = in_sizes[1];  // 120000
  const int N1D = in_sizes[2];  // 30000
  const int E1  = in_sizes[3];  // 960000
  const int N2D = in_sizes[5];  // 6000
  const int E2  = in_sizes[6];  // 192000
  const int NTOT = N1D + N2D;
  const int ETOT = E1 + E2;

  char* w = (char*)d_ws;
  size_t off = 0;
  auto alloc = [&](size_t bytes) -> void* {
    void* p = (void*)(w + off);
    off += (bytes + 255) & ~(size_t)255;
    return p;
  };
  ushort_t* hs1 = (ushort_t*)alloc((size_t)N1 * 64 * 2);  // bf16 intermediate
  float* ssrc1 = (float*)alloc((size_t)N1 * 8 * 4);
  float* hs2   = (float*)alloc((size_t)N1D * 41 * 4);
  float* ssrc2 = (float*)alloc((size_t)N1D * 4);
  int* counts  = (int*)alloc((size_t)NTOT * 4);  // memset below covers exactly this
  int* offs    = (int*)alloc((size_t)(NTOT + 1) * 4);
  int* bsum    = (int*)alloc((size_t)256 * 4);
  int* epay    = (int*)alloc((size_t)ETOT * 4);
  int* erank   = (int*)alloc((size_t)ETOT * 4);
  short* Wp    = (short*)alloc((size_t)19 * 4 * 64 * 8 * 2);
  (void)ws_size; (void)n_in; (void)out_size;

  hipMemsetAsync(counts, 0, (size_t)NTOT * 4, stream);

  // CSR build: hist (rank-recording) fused with W1 prepack, then 2-pass scan
  const int nbE = (ETOT + 255) / 256;
  const int nb = (NTOT + 255) / 256;  // 141 (<= 256: scan3 self-computes prefix)
  hist_prepack_kernel<<<nbE + 19, 256, 0, stream>>>(edst1, edst2, counts, erank, W1, Wp,
                                                    E1, E2, N1D, nbE);
  scan1_kernel<<<nb, 256, 0, stream>>>(counts, offs, bsum, NTOT);
  scan3_kernel<<<nb, 256, 0, stream>>>(offs, bsum, NTOT, ETOT, nb);

  // layer 1: scatter blocks FIRST (latency hides under the HBM-bound GEMM),
  // then GEMM1 + attn-src epilogue blocks
  const int nbG = (N1 + 63) / 64;
  gemm1_fused_kernel<<<nbE + nbG, 256, 0, stream>>>(
      x, n_id1, Wp, as1, hs1, ssrc1, N1, nbE,
      edst1, esrc1, edst2, esrc2, offs, erank, epay, E1, E2, N1D);
  agg1_kernel<<<(N1D + 3) / 4, 256, 0, stream>>>(offs, epay, ssrc1, res1, ad1, hs1, b1,
                                                 W2, as2, hs2, ssrc2, N1D);

  // layer 2 (CSR segment 2 lives at offs + N1D, payload is layer-2 src node id)
  agg2_kernel<<<(N2D + 3) / 4, 256, 0, stream>>>(offs + N1D, epay, ssrc2, res2, ad2, hs2, b2, out, N2D);
}

// Round 3
// 783.441 us; speedup vs baseline: 1.0690x; 1.0025x over previous
//
#include <hip/hip_runtime.h>
#include <hip/hip_bf16.h>
#include <math.h>

typedef __attribute__((ext_vector_type(8))) short short8;
typedef __attribute__((ext_vector_type(4))) float float4v;
typedef unsigned short ushort_t;

// ---------------- helpers ----------------
__device__ __forceinline__ float wave_max64(float v) {
#pragma unroll
  for (int o = 32; o > 0; o >>= 1) v = fmaxf(v, __shfl_xor(v, o));
  return v;
}
__device__ __forceinline__ float wave_sum64(float v) {
#pragma unroll
  for (int o = 32; o > 0; o >>= 1) v += __shfl_xor(v, o);
  return v;
}
__device__ __forceinline__ int wave_isum64(int v) {
#pragma unroll
  for (int o = 32; o > 0; o >>= 1) v += __shfl_xor(v, o);
  return v;
}
__device__ __forceinline__ float lrelu02(float v) { return v > 0.f ? v : 0.2f * v; }
__device__ __forceinline__ short bf16_rne(float f) {
  unsigned u = __builtin_bit_cast(unsigned, f);
  unsigned r = (u + 0x7FFFu + ((u >> 16) & 1u)) >> 16;
  return (short)r;
}
__device__ __forceinline__ float bf16_to_f32(ushort_t u) {
  return __builtin_bit_cast(float, ((unsigned)u) << 16);
}

// ---------------- hist (4 edges/thread, records per-edge rank) + W1 prepack -----------
// blocks [0, nbE4): histogram, int4-vectorized (ETOT = 1152000 is divisible by 4;
//   guards kept for generality). The atomicAdd return value IS the edge's unique
//   rank within its dst segment -> erank, so scatter needs no second atomic.
// blocks [nbE4, nbE4+19): prepack W1 into MFMA B-fragment order:
// Wp[((s*4+t)*64+lane)*8+j] = bf16(W[k][n]), k = s*32+(lane>>4)*8+j, n = t*16+(lane&15).
__global__ void hist_prepack_kernel(const int* __restrict__ dst1, const int* __restrict__ dst2,
                                    int* __restrict__ counts, int* __restrict__ erank,
                                    const float* __restrict__ W,
                                    short* __restrict__ Wp, int E1, int E2, int N1D, int nbE4) {
  int b = blockIdx.x;
  if (b < nbE4) {
    int base = (b * 256 + threadIdx.x) * 4;
    if (base + 3 < E1) {
      int4 d = *(const int4*)(dst1 + base);
      int4 r;
      r.x = atomicAdd(&counts[d.x], 1);
      r.y = atomicAdd(&counts[d.y], 1);
      r.z = atomicAdd(&counts[d.z], 1);
      r.w = atomicAdd(&counts[d.w], 1);
      *(int4*)(erank + base) = r;
    } else if (base < E1) {  // generic tail (not hit for E1 % 4 == 0)
      for (int j = 0; j < 4 && base + j < E1; j++)
        erank[base + j] = atomicAdd(&counts[dst1[base + j]], 1);
    } else {
      int base2 = base - E1;
      if (base2 + 3 < E2) {
        int4 d = *(const int4*)(dst2 + base2);
        int4 r;
        r.x = atomicAdd(&counts[N1D + d.x], 1);
        r.y = atomicAdd(&counts[N1D + d.y], 1);
        r.z = atomicAdd(&counts[N1D + d.z], 1);
        r.w = atomicAdd(&counts[N1D + d.w], 1);
        *(int4*)(erank + base) = r;
      } else {
        for (int j = 0; j < 4 && base2 + j < E2; j++)
          erank[base + j] = atomicAdd(&counts[N1D + dst2[base2 + j]], 1);
      }
    }
  } else {
    int idx = (b - nbE4) * 256 + threadIdx.x;  // over 19*4*64 = 4864
    if (idx >= 19 * 4 * 64) return;
    int lane = idx & 63;
    int t = (idx >> 6) & 3;
    int s = idx >> 8;
    int quad = lane >> 4, n = t * 16 + (lane & 15);
    short8 v;
#pragma unroll
    for (int j = 0; j < 8; j++) {
      int k = s * 32 + quad * 8 + j;
      v[j] = (k < 602) ? bf16_rne(W[k * 64 + n]) : (short)0;
    }
    *((short8*)Wp + idx) = v;
  }
}

// ---------------- single-kernel scan (fused old scan1+scan2+scan3) --------------------
// nb = 141 blocks <= 256 CUs with trivial resources -> ALL blocks are co-resident
// (>=1 block/CU floor), so a device-scope atomic barrier cannot deadlock.
// Each block: local exclusive scan -> publish block total (release) -> barrier spin
// -> self-compute prefix over preceding block totals (nb <= 256) -> finalize offs.
__global__ __launch_bounds__(256) void scan_kernel(const int* __restrict__ counts,
                                                   int* __restrict__ offs,
                                                   int* __restrict__ bsum,
                                                   int* __restrict__ done,
                                                   int n, int etot, int nb) {
  __shared__ int ws[4], wpre[4], wsum[4];
  int tid = threadIdx.x, lane = tid & 63, w = tid >> 6;
  int bid = blockIdx.x;
  int i = bid * 256 + tid;
  int v = (i < n) ? counts[i] : 0;
  int x = v;
#pragma unroll
  for (int o = 1; o < 64; o <<= 1) {
    int y = __shfl_up(x, o);
    if (lane >= o) x += y;
  }
  if (lane == 63) ws[w] = x;
  __syncthreads();
  if (tid == 0) {
    int run = 0;
#pragma unroll
    for (int k = 0; k < 4; k++) { wpre[k] = run; run += ws[k]; }
    __hip_atomic_store(&bsum[bid], run, __ATOMIC_RELEASE, __HIP_MEMORY_SCOPE_AGENT);
    __hip_atomic_fetch_add(done, 1, __ATOMIC_RELEASE, __HIP_MEMORY_SCOPE_AGENT);
    while (__hip_atomic_load(done, __ATOMIC_ACQUIRE, __HIP_MEMORY_SCOPE_AGENT) < nb) {}
  }
  __syncthreads();  // every thread waits for the lane-0 spin
  int pv = (tid < nb && tid < bid)
               ? __hip_atomic_load(&bsum[tid], __ATOMIC_RELAXED, __HIP_MEMORY_SCOPE_AGENT)
               : 0;
  pv = wave_isum64(pv);
  if (lane == 0) wsum[w] = pv;
  __syncthreads();
  int pre = wsum[0] + wsum[1] + wsum[2] + wsum[3];
  if (i < n) offs[i] = x - v + wpre[w] + pre;
  if (i == 0) offs[n] = etot;  // sentinel
}

// ---------------- fused: edge scatter + GEMM1 (MFMA bf16) + attn-src epilogue --------
// blocks [0, nbE4): CSR payload scatter, int4-vectorized, placed FIRST so its
//   gather/store latency hides under the HBM-bound GEMM blocks that follow.
//   pos = offs[d] + erank[e]; payload is the SOURCE NODE id (order-independent agg).
// blocks [nbE4, nbE4+nbG): hs1 = bf16(x[n_id1] @ W1) (wave = 16 rows x 64 cols),
//   x-gather software-pipelined one k-step ahead so HBM latency hides under
//   cvt+MFMA of the current step. Per-head attn-src logits reduced straight out
//   of the f32 accumulators: col c = t*16+mrow -> head h = t*2+(mrow>>3);
//   8-lane shfl_xor(1,2,4) over mrow&7 yields ssrc1[r*8+h] for free.
__global__ __launch_bounds__(256) void gemm1_fused_kernel(
    const float* __restrict__ x, const int* __restrict__ n_id,
    const short* __restrict__ Wp, const float* __restrict__ as1,
    ushort_t* __restrict__ out, float* __restrict__ ssrc1, int M, int nbE4,
    const int* __restrict__ dst1, const int* __restrict__ src1,
    const int* __restrict__ dst2, const int* __restrict__ src2,
    const int* __restrict__ offs, const int* __restrict__ erank,
    int* __restrict__ epay, int E1, int E2, int N1D) {
  if (blockIdx.x < nbE4) {
    int base = (blockIdx.x * 256 + threadIdx.x) * 4;
    if (base + 3 < E1) {
      int4 d = *(const int4*)(dst1 + base);
      int4 s = *(const int4*)(src1 + base);
      int4 r = *(const int4*)(erank + base);
      epay[offs[d.x] + r.x] = s.x;
      epay[offs[d.y] + r.y] = s.y;
      epay[offs[d.z] + r.z] = s.z;
      epay[offs[d.w] + r.w] = s.w;
    } else if (base < E1) {
      for (int j = 0; j < 4 && base + j < E1; j++)
        epay[offs[dst1[base + j]] + erank[base + j]] = src1[base + j];
    } else {
      int base2 = base - E1;
      if (base2 + 3 < E2) {
        int4 d = *(const int4*)(dst2 + base2);
        int4 s = *(const int4*)(src2 + base2);
        int4 r = *(const int4*)(erank + base);
        epay[offs[N1D + d.x] + r.x] = s.x;
        epay[offs[N1D + d.y] + r.y] = s.y;
        epay[offs[N1D + d.z] + r.z] = s.z;
        epay[offs[N1D + d.w] + r.w] = s.w;
      } else {
        for (int j = 0; j < 4 && base2 + j < E2; j++)
          epay[offs[N1D + dst2[base2 + j]] + erank[base + j]] = src2[base2 + j];
      }
    }
    return;
  }
  constexpr int K = 602, NSTEP = 19;
  int gb = blockIdx.x - nbE4;
  int tid = threadIdx.x;
  int wid = tid >> 6, lane = tid & 63;
  int quad = lane >> 4, mrow = lane & 15;
  int r = gb * 64 + wid * 16 + mrow;
  int grow = n_id[r < M ? r : M - 1];
  const float* xrow = x + (size_t)grow * K;
  float4v acc[4] = {{0.f, 0.f, 0.f, 0.f}, {0.f, 0.f, 0.f, 0.f},
                    {0.f, 0.f, 0.f, 0.f}, {0.f, 0.f, 0.f, 0.f}};
  float2 cur[4], nxt[4];
  auto ld = [&](int s, float2* b) {
    int k0 = s * 32 + quad * 8;
    if (k0 + 8 <= K) {  // 8B-aligned (row pitch 602 even, k0 even)
#pragma unroll
      for (int j = 0; j < 4; j++) b[j] = *(const float2*)(xrow + k0 + 2 * j);
    } else {
#pragma unroll
      for (int j = 0; j < 4; j++) {
        int k = k0 + 2 * j;
        float2 t;
        t.x = (k < K) ? xrow[k] : 0.f;
        t.y = (k + 1 < K) ? xrow[k + 1] : 0.f;
        b[j] = t;
      }
    }
  };
  ld(0, cur);
  for (int s = 0; s < NSTEP; s++) {
    if (s + 1 < NSTEP) ld(s + 1, nxt);  // prefetch next 32B chunk under this step's MFMA
    short8 a;
#pragma unroll
    for (int j = 0; j < 4; j++) {
      a[2 * j] = bf16_rne(cur[j].x);
      a[2 * j + 1] = bf16_rne(cur[j].y);
    }
    const short8* wp = (const short8*)Wp + (size_t)s * 256 + lane;
#pragma unroll
    for (int t = 0; t < 4; t++) {
      short8 bfr = wp[t * 64];
      acc[t] = __builtin_amdgcn_mfma_f32_16x16x32_bf16(a, bfr, acc[t], 0, 0, 0);
    }
#pragma unroll
    for (int j = 0; j < 4; j++) cur[j] = nxt[j];
  }
  int rb = gb * 64 + wid * 16;
#pragma unroll
  for (int t = 0; t < 4; t++) {
#pragma unroll
    for (int j = 0; j < 4; j++) {
      int rr = rb + quad * 4 + j;  // C/D: col = lane&15, row = quad*4 + reg
      if (rr < M) out[(size_t)rr * 64 + t * 16 + mrow] = (ushort_t)bf16_rne(acc[t][j]);
    }
  }
  // attn-src epilogue (f32 accumulators -> full-precision logits)
  float afv[4];
#pragma unroll
  for (int t = 0; t < 4; t++) afv[t] = as1[t * 16 + mrow];  // as1_flat[c], c=t*16+mrow
#pragma unroll
  for (int t = 0; t < 4; t++) {
#pragma unroll
    for (int j = 0; j < 4; j++) {
      float v = acc[t][j] * afv[t];
      v += __shfl_xor(v, 1);  // reduce over mrow&7 (lane bits 0..2)
      v += __shfl_xor(v, 2);
      v += __shfl_xor(v, 4);
      if ((lane & 7) == 0) {
        int rr = rb + quad * 4 + j;
        if (rr < M) ssrc1[rr * 8 + t * 2 + ((lane >> 3) & 1)] = v;
      }
    }
  }
}

// ---------------- aggregation layer 1 (online softmax, fused attn_dst)
//                  + fused GEMM2 / attn-src2 tail -----------------------------
// hs1 is stored bf16 (pure intermediate; f32 accumulation here). At the end of
// each wave the full 64-element h1 row (post bias+ELU) lives in registers ->
// compute hs2[wid] = h1_row @ W2 and ssrc2[wid] via a per-wave LDS row broadcast
// (no h1 buffer round-trip, no gemm2 launch).
__global__ __launch_bounds__(256) void agg1_kernel(
    const int* __restrict__ offs, const int* __restrict__ srcs,
    const float* __restrict__ s_src, const int* __restrict__ res,
    const float* __restrict__ ad, const ushort_t* __restrict__ hs1,
    const float* __restrict__ bias, const float* __restrict__ W2,
    const float* __restrict__ as2, float* __restrict__ hs2,
    float* __restrict__ ssrc2, int n_dst) {
  constexpr int C = 41;
  __shared__ float Ws[64 * C];
  __shared__ float rowsh[4][64];
  for (int i = threadIdx.x; i < 64 * C; i += 256) Ws[i] = W2[i];
  __syncthreads();
  int wid = (blockIdx.x * blockDim.x + threadIdx.x) >> 6;
  if (wid >= n_dst) return;
  int lane = threadIdx.x & 63;
  int w = threadIdx.x >> 6;
  int h = lane >> 3;
  // fused attn_dst1: sd[h] = dot(hs1[res[wid], h*8:h*8+8], ad[h*8:h*8+8])
  int node = res[wid];
  float v = bf16_to_f32(hs1[(size_t)node * 64 + lane]) * ad[lane];
  v += __shfl_xor(v, 1);
  v += __shfl_xor(v, 2);
  v += __shfl_xor(v, 4);
  float sd = v;  // per-8-lane head group sum
  int beg = offs[wid], end = offs[wid + 1];
  float mx = -1e30f, den = 0.f, acc = 0.f;
  for (int i = beg; i < end; i += 8) {
    int m = end - i; if (m > 8) m = 8;
    int sr[8]; float ss[8], row[8];
#pragma unroll
    for (int j = 0; j < 8; j++) sr[j] = srcs[i + (j < m ? j : 0)];
#pragma unroll
    for (int j = 0; j < 8; j++) ss[j] = s_src[sr[j] * 8 + h];
#pragma unroll
    for (int j = 0; j < 8; j++) row[j] = bf16_to_f32(hs1[(size_t)sr[j] * 64 + lane]);
    float p[8];
#pragma unroll
    for (int j = 0; j < 8; j++) p[j] = (j < m) ? lrelu02(ss[j] + sd) : -1e30f;
    float bm = mx;
#pragma unroll
    for (int j = 0; j < 8; j++) bm = fmaxf(bm, p[j]);
    float scale = __expf(mx - bm);
    den *= scale;
    acc *= scale;
#pragma unroll
    for (int j = 0; j < 8; j++) {
      float w2 = __expf(p[j] - bm);
      den += w2;
      acc += w2 * row[j];
    }
    mx = bm;
  }
  float val = (end > beg) ? acc / den : 0.f;
  val += bias[lane];
  val = val > 0.f ? val : __expf(val) - 1.f;  // ELU  -> h1[wid][lane]
  // fused GEMM2 row: hs2[wid][c] = sum_k h1[wid][k] * W2[k][c]
  // (wave-local LDS transpose: same wave produces and consumes; lgkmcnt orders)
  rowsh[w][lane] = val;
  float acc2 = 0.f;
  if (lane < C) {
#pragma unroll 8
    for (int k = 0; k < 64; k++) acc2 += rowsh[w][k] * Ws[k * C + lane];
  }
  float tt = (lane < C) ? acc2 * as2[lane] : 0.f;
  tt = wave_sum64(tt);
  if (lane == 0) ssrc2[wid] = tt;
  if (lane < C) hs2[(size_t)wid * C + lane] = acc2;
}

// ---------------- aggregation layer 2 (online softmax, fused attn_dst) + log_softmax ----
__global__ __launch_bounds__(256) void agg2_kernel(
    const int* __restrict__ offs, const int* __restrict__ srcs,
    const float* __restrict__ s_src, const int* __restrict__ res,
    const float* __restrict__ ad, const float* __restrict__ hs2,
    const float* __restrict__ bias, float* __restrict__ out, int n_dst) {
  constexpr int C = 41;
  int wid = (blockIdx.x * blockDim.x + threadIdx.x) >> 6;
  if (wid >= n_dst) return;
  int lane = threadIdx.x & 63;
  bool act = lane < C;
  // fused attn_dst2: sd = dot(hs2[res[wid]], ad)
  int node = res[wid];
  float dv = act ? hs2[(size_t)node * C + lane] * ad[lane] : 0.f;
  float sd = wave_sum64(dv);
  int beg = offs[wid], end = offs[wid + 1];
  float mx = -1e30f, den = 0.f, acc = 0.f;
  for (int i = beg; i < end; i += 8) {
    int m = end - i; if (m > 8) m = 8;
    int sr[8]; float ss[8], row[8];
#pragma unroll
    for (int j = 0; j < 8; j++) sr[j] = srcs[i + (j < m ? j : 0)];
#pragma unroll
    for (int j = 0; j < 8; j++) ss[j] = s_src[sr[j]];
#pragma unroll
    for (int j = 0; j < 8; j++) row[j] = act ? hs2[(size_t)sr[j] * C + lane] : 0.f;
    float p[8];
#pragma unroll
    for (int j = 0; j < 8; j++) p[j] = (j < m) ? lrelu02(ss[j] + sd) : -1e30f;
    float bm = mx;
#pragma unroll
    for (int j = 0; j < 8; j++) bm = fmaxf(bm, p[j]);
    float scale = __expf(mx - bm);
    den *= scale;
    acc *= scale;
#pragma unroll
    for (int j = 0; j < 8; j++) {
      float w = __expf(p[j] - bm);
      den += w;
      acc += w * row[j];
    }
    mx = bm;
  }
  float val = (end > beg) ? acc / den : 0.f;
  if (act) val += bias[lane];
  float lv = act ? val : -1e30f;
  float m2 = wave_max64(lv);
  float ex = act ? __expf(val - m2) : 0.f;
  float ssum = wave_sum64(ex);
  if (act) out[(size_t)wid * C + lane] = val - m2 - __logf(ssum);
}

// ---------------- launch ----------------
extern "C" void kernel_launch(void* const* d_in, const int* in_sizes, int n_in,
                              void* d_out, int out_size, void* d_ws, size_t ws_size,
                              hipStream_t stream) {
  const float* x    = (const float*)d_in[0];
  const int* n_id1  = (const int*)d_in[1];
  const int* res1   = (const int*)d_in[2];
  const int* esrc1  = (const int*)d_in[3];
  const int* edst1  = (const int*)d_in[4];
  const int* res2   = (const int*)d_in[5];
  const int* esrc2  = (const int*)d_in[6];
  const int* edst2  = (const int*)d_in[7];
  const float* W1   = (const float*)d_in[8];
  const float* as1  = (const float*)d_in[9];
  const float* ad1  = (const float*)d_in[10];
  const float* b1   = (const float*)d_in[11];
  const float* W2   = (const float*)d_in[12];
  const float* as2  = (const float*)d_in[13];
  const float* ad2  = (const float*)d_in[14];
  const float* b2   = (const float*)d_in[15];
  float* out = (float*)d_out;

  const int N1  = in_sizes[1];  // 120000
  const int N1D = in_sizes[2];  // 30000
  const int E1  = in_sizes[3];  // 960000
  const int N2D = in_sizes[5];  // 6000
  const int E2  = in_sizes[6];  // 192000
  const int NTOT = N1D + N2D;
  const int ETOT = E1 + E2;

  char* w = (char*)d_ws;
  size_t off = 0;
  auto alloc = [&](size_t bytes) -> void* {
    void* p = (void*)(w + off);
    off += (bytes + 255) & ~(size_t)255;
    return p;
  };
  ushort_t* hs1 = (ushort_t*)alloc((size_t)N1 * 64 * 2);  // bf16 intermediate
  float* ssrc1 = (float*)alloc((size_t)N1 * 8 * 4);
  float* hs2   = (float*)alloc((size_t)N1D * 41 * 4);
  float* ssrc2 = (float*)alloc((size_t)N1D * 4);
  // counts + done flag in ONE contiguous alloc; the memset below covers exactly
  // (NTOT+1) ints so the scan barrier flag is re-zeroed on every graph replay.
  int* counts  = (int*)alloc((size_t)(NTOT + 1) * 4);
  int* done    = counts + NTOT;
  int* offs    = (int*)alloc((size_t)(NTOT + 1) * 4);
  int* bsum    = (int*)alloc((size_t)256 * 4);
  int* epay    = (int*)alloc((size_t)ETOT * 4);
  int* erank   = (int*)alloc((size_t)ETOT * 4);
  short* Wp    = (short*)alloc((size_t)19 * 4 * 64 * 8 * 2);
  (void)ws_size; (void)n_in; (void)out_size;

  hipMemsetAsync(counts, 0, (size_t)(NTOT + 1) * 4, stream);

  // CSR build: hist (rank-recording, 4 edges/thread) fused with W1 prepack,
  // then ONE scan kernel (141 co-resident blocks, device-atomic barrier)
  const int nbE4 = (ETOT + 1023) / 1024;  // 1125
  const int nb = (NTOT + 255) / 256;      // 141 (<= 256 CUs: all co-resident)
  hist_prepack_kernel<<<nbE4 + 19, 256, 0, stream>>>(edst1, edst2, counts, erank, W1, Wp,
                                                     E1, E2, N1D, nbE4);
  scan_kernel<<<nb, 256, 0, stream>>>(counts, offs, bsum, done, NTOT, ETOT, nb);

  // layer 1: scatter blocks FIRST (latency hides under the HBM-bound GEMM),
  // then GEMM1 + attn-src epilogue blocks
  const int nbG = (N1 + 63) / 64;
  gemm1_fused_kernel<<<nbE4 + nbG, 256, 0, stream>>>(
      x, n_id1, Wp, as1, hs1, ssrc1, N1, nbE4,
      edst1, esrc1, edst2, esrc2, offs, erank, epay, E1, E2, N1D);
  agg1_kernel<<<(N1D + 3) / 4, 256, 0, stream>>>(offs, epay, ssrc1, res1, ad1, hs1, b1,
                                                 W2, as2, hs2, ssrc2, N1D);

  // layer 2 (CSR segment 2 lives at offs + N1D, payload is layer-2 src node id)
  agg2_kernel<<<(N2D + 3) / 4, 256, 0, stream>>>(offs + N1D, epay, ssrc2, res2, ad2, hs2, b2, out, N2D);
}